// Round 1
// baseline (220.811 us; speedup 1.0000x reference)
//
#include <hip/hip_runtime.h>
#include <math.h>

#define NSTEPS 216
#define BLK 64
#define ZSTRIDE 217   // odd stride in halfwords -> max 2-way LDS bank aliasing (free)

// Batch-independent trajectory tables, recomputed every call (graph-safe).
__device__ float g_th[NSTEPS];
__device__ float g_z0[NSTEPS];

__global__ void traj_kernel() {
    const int t = threadIdx.x;
    if (t < NSTEPS) {
        // ts = arange(216)/216 (f32); z0 = 0.005*sin((2*pi*0.25 as f32)*t)
        float tf = (float)t / 216.0f;
        g_z0[t] = 0.005f * sinf((float)(0.5 * M_PI) * tf);
    }
    if (t == 0) {
        // x,y recurrence is identical across the whole batch: run it once, f32,
        // same op order as the reference.
        float x = (float)(-0.417750770388669);
        float y = (float)(-0.9085616622823985);
        const float W = (float)(2.0 * M_PI);
        const float H = (float)(1.0 / 216.0);
        for (int n = 0; n < NSTEPS; ++n) {
            g_th[n] = atan2f(y, x);                  // th uses pre-update x,y
            float alpha = 1.0f - sqrtf(x * x + y * y);
            float fx = alpha * x - W * y;
            float fy = alpha * y + W * x;
            x = x + H * fx;
            y = y + H * fy;
        }
    }
}

__global__ __launch_bounds__(BLK) void euler_kernel(const float* __restrict__ prm,
                                                    const float* __restrict__ v0,
                                                    float* __restrict__ out) {
    __shared__ float th_s[NSTEPS];
    __shared__ float z0_s[NSTEPS];
    __shared__ float sc_s[BLK];
    __shared__ float of_s[BLK];
    __shared__ _Float16 z_s[BLK * ZSTRIDE];   // per-row z trajectory, fp16 snapshot

    const int tid = threadIdx.x;
    for (int i = tid; i < NSTEPS; i += BLK) {
        th_s[i] = g_th[i];
        z0_s[i] = g_z0[i];
    }

    const int b = blockIdx.x * BLK + tid;
    const float* p = prm + (size_t)b * 15;

    float aj[5], tj[5], cj[5];
#pragma unroll
    for (int j = 0; j < 5; ++j) {
        aj[j] = p[3 * j + 0];
        float bb = p[3 * j + 1];
        cj[j] = -1.0f / (2.0f * bb * bb);   // exp(-d^2/(2 b^2)) = __expf(d^2 * cj)
        tj[j] = p[3 * j + 2];
    }

    float z = v0[b];
    float zmin = 3.4e38f, zmax = -3.4e38f;
    const float H = (float)(1.0 / 216.0);

    __syncthreads();

    _Float16* zrow = z_s + tid * ZSTRIDE;
#pragma unroll 4
    for (int t = 0; t < NSTEPS; ++t) {
        float th = th_s[t];
        float G = 0.0f;
#pragma unroll
        for (int j = 0; j < 5; ++j) {
            float d = th - tj[j];
            G += aj[j] * d * __expf(d * d * cj[j]);
        }
        float fz = z0_s[t] - z - G;          // = -G - (z - z0_t)
        z = z + H * fz;
        zmin = fminf(zmin, z);
        zmax = fmaxf(zmax, z);
        zrow[t] = (_Float16)z;
    }

    // out = (z - zmin) * MAX/(zmax - zmin) + MIN  ==  z*s + (MIN - zmin*s)
    float s = 0.042557f / (zmax - zmin);
    sc_s[tid] = s;
    of_s[tid] = fmaf(-zmin, s, -0.01563f);

    __syncthreads();

    // Coalesced float4 write-out of this block's 64 rows in natural (B,216) layout.
    float* outB = out + (size_t)blockIdx.x * (BLK * NSTEPS);
    const int TOT = BLK * NSTEPS;            // 13824
    for (int base = tid * 4; base < TOT; base += BLK * 4) {
        float4 v;
        float* vp = &v.x;
#pragma unroll
        for (int k = 0; k < 4; ++k) {
            int idx = base + k;
            int r = (int)(((unsigned long long)idx * 19884108ull) >> 32);  // idx/216
            int t = idx - r * 216;
            float zz = (float)z_s[r * ZSTRIDE + t];
            vp[k] = fmaf(zz, sc_s[r], of_s[r]);
        }
        *(float4*)(outB + base) = v;
    }
}

extern "C" void kernel_launch(void* const* d_in, const int* in_sizes, int n_in,
                              void* d_out, int out_size, void* d_ws, size_t ws_size,
                              hipStream_t stream) {
    const float* x  = (const float*)d_in[0];
    const float* v0 = (const float*)d_in[1];
    float* out = (float*)d_out;
    const int nb = in_sizes[1];              // 131072 batch rows

    hipLaunchKernelGGL(traj_kernel, dim3(1), dim3(256), 0, stream);
    hipLaunchKernelGGL(euler_kernel, dim3(nb / BLK), dim3(BLK), 0, stream, x, v0, out);
}

// Round 3
// 191.730 us; speedup vs baseline: 1.1517x; 1.1517x over previous
//
#include <hip/hip_runtime.h>
#include <math.h>

#define NSTEPS 216
#define BLK 64
#define CT 54          // output-staging chunk (216 = 4*54)
#define CSTR 55        // LDS stride, odd -> coprime with 32 banks

// Batch-independent per-step tables, recomputed every call (graph-safe).
__device__ float g_th[NSTEPS];    // atan2 trajectory
__device__ float g_hz0[NSTEPS];   // H * z0_t

__global__ void traj_kernel() {
    __shared__ float xs[NSTEPS], ys[NSTEPS];
    const int t = threadIdx.x;
    if (t == 0) {
        // Serial part: only the cheap x/y recurrence (sqrt + FMAs).
        float x = (float)(-0.417750770388669);
        float y = (float)(-0.9085616622823985);
        const float W = (float)(2.0 * M_PI);
        const float H = (float)(1.0 / 216.0);
        for (int n = 0; n < NSTEPS; ++n) {
            xs[n] = x;                      // th uses pre-update x,y
            ys[n] = y;
            float alpha = 1.0f - sqrtf(x * x + y * y);
            float fx = alpha * x - W * y;
            float fy = alpha * y + W * x;
            x = x + H * fx;
            y = y + H * fy;
        }
    }
    __syncthreads();
    if (t < NSTEPS) {
        g_th[t] = atan2f(ys[t], xs[t]);     // 216 atan2s in parallel
        float tf = (float)t / 216.0f;
        g_hz0[t] = (float)(1.0 / 216.0) * (0.005f * sinf(1.5707964f * tf));
    }
}

__global__ __launch_bounds__(BLK) void euler_kernel(const float* __restrict__ prm,
                                                    const float* __restrict__ v0,
                                                    float* __restrict__ out) {
    __shared__ float th_s[NSTEPS];
    __shared__ float hz0_s[NSTEPS];
    __shared__ float st_s[BLK * CSTR];   // 64 rows x 54 scaled outputs, stride 55

    const int tid = threadIdx.x;
    for (int i = tid; i < NSTEPS; i += BLK) {
        th_s[i] = g_th[i];
        hz0_s[i] = g_hz0[i];
    }

    const int b = blockIdx.x * BLK + tid;
    const float* p = prm + (size_t)b * 15;

    // gaussian_j(d) = a*d*exp(-d^2/(2b^2)) = d * exp(d^2*c + ln a)
    float tj[5], cj[5], la[5];
#pragma unroll
    for (int j = 0; j < 5; ++j) {
        float a  = p[3 * j + 0];
        float bb = p[3 * j + 1];
        tj[j] = p[3 * j + 2];
        cj[j] = -1.0f / (2.0f * bb * bb);
        la[j] = __logf(a);
    }

    const float zinit = v0[b];
    const float H = (float)(1.0 / 216.0);
    const float K = 1.0f - H;            // z_n = z*K + (H*z0_t - H*G)

    __syncthreads();

    // ---- pass 1: min/max only (no trajectory storage) ----
    float z = zinit;
    float zmin = 3.4e38f, zmax = -3.4e38f;
#pragma unroll 4
    for (int t = 0; t < NSTEPS; ++t) {
        float th = th_s[t];
        float G = 0.0f;
#pragma unroll
        for (int j = 0; j < 5; ++j) {
            float d = th - tj[j];
            G = fmaf(d, __expf(fmaf(d * d, cj[j], la[j])), G);
        }
        z = fmaf(z, K, fmaf(-H, G, hz0_s[t]));
        zmin = fminf(zmin, z);
        zmax = fmaxf(zmax, z);
    }
    const float s = 0.042557f / (zmax - zmin);
    const float o = fmaf(-zmin, s, -0.01563f);

    // ---- pass 2: recompute (bit-identical z), scale, coalesced write ----
    z = zinit;
    float* outB = out + (size_t)blockIdx.x * (BLK * NSTEPS);
    for (int c0 = 0; c0 < NSTEPS; c0 += CT) {
#pragma unroll 4
        for (int tc = 0; tc < CT; ++tc) {
            int t = c0 + tc;
            float th = th_s[t];
            float G = 0.0f;
#pragma unroll
            for (int j = 0; j < 5; ++j) {
                float d = th - tj[j];
                G = fmaf(d, __expf(fmaf(d * d, cj[j], la[j])), G);
            }
            z = fmaf(z, K, fmaf(-H, G, hz0_s[t]));
            st_s[tid * CSTR + tc] = fmaf(z, s, o);
        }
        __syncthreads();
        // 64*54 staged elements -> natural (row,col) layout, 216B runs/row.
        // idx/54 via compiler-generated reciprocal (hand-rolled magic was the
        // R2 OOB bug: (idx*1214)>>16 gives 64 at idx=3455).
#pragma unroll 6
        for (int k = 0; k < CT; ++k) {
            unsigned idx = (unsigned)tid + BLK * k;
            unsigned r = idx / 54u;
            unsigned tt = idx - r * 54u;
            outB[r * NSTEPS + c0 + tt] = st_s[r * CSTR + tt];
        }
        __syncthreads();
    }
}

extern "C" void kernel_launch(void* const* d_in, const int* in_sizes, int n_in,
                              void* d_out, int out_size, void* d_ws, size_t ws_size,
                              hipStream_t stream) {
    const float* x  = (const float*)d_in[0];
    const float* v0 = (const float*)d_in[1];
    float* out = (float*)d_out;
    const int nb = in_sizes[1];              // 131072 batch rows

    hipLaunchKernelGGL(traj_kernel, dim3(1), dim3(256), 0, stream);
    hipLaunchKernelGGL(euler_kernel, dim3(nb / BLK), dim3(BLK), 0, stream, x, v0, out);
}